// Round 7
// baseline (226.629 us; speedup 1.0000x reference)
//
#include <hip/hip_runtime.h>

// Problem constants (fixed by setup_inputs): B=8, P=25000, C=81, E=256, N=B*P=200000
#define N_TOT   200000
#define C_CLS   81
#define P_PER   25000
#define CM1     80            // C-1

// Output layout (float32 elements, concatenated in return order):
//   boxes   [N,80,4]  -> offset 0,           size 64,000,000
//   scores  [N,80]    -> offset 64,000,000,  size 16,000,000
//   id_embs [N,256]   -> offset 80,000,000,  size 51,200,000
//   labels  [N,80]    -> offset 131,200,000, size 16,000,000
//   roi     [N,80]    -> offset 147,200,000, size 16,000,000

typedef float f4 __attribute__((ext_vector_type(4)));

// Fused grid partition (256-thread blocks). Rules learned:
//  R5: every wave-level NT store must cover a CONTIGUOUS span (lane i at
//      base + i*16B); scattered 16B fragments inflate WRITE_SIZE 1.6x.
//  R3: NT stores (L2/L3 no-allocate) beat cached stores by ~5% for the
//      653 MB single-touch write streams.
//  R7 test: plain CACHED loads (inputs are immutable across replays; NT
//      stores leave all 256MB L3 free to retain input) vs NT loads.
#define DEC_BLOCKS 62500u
#define SM_BLOCKS  50000u
#define CP_BLOCKS  25000u
#define LR_BLOCKS  15625u
#define SM_BASE    (DEC_BLOCKS)
#define CP_BASE    (DEC_BLOCKS + SM_BLOCKS)
#define LR_BASE    (DEC_BLOCKS + SM_BLOCKS + CP_BLOCKS)
#define CP_HALF    6400000u   // float4s per half of id_emb (12.8M / 2)

__global__ __launch_bounds__(256) void fused_kernel(
    const float* __restrict__ logits,      // [N, 81]
    const f4*    __restrict__ box_reg4,    // [N, 81] float4 rows
    const f4*    __restrict__ id_emb4,     // [N*64] float4
    const f4*    __restrict__ proposals4,  // [N]
    const int*   __restrict__ img_h_p,
    const int*   __restrict__ img_w_p,
    float* __restrict__ out)
{
    __shared__ float sbuf[4][80];                   // softmax row staging

    f4*    out_boxes   = (f4*)out;                  // [16M] float4
    f4*    out_scores4 = (f4*)(out + 64000000u);    // [4M]  float4 (80%4==0)
    f4*    out_ids     = (f4*)(out + 80000000u);
    f4*    out_labels4 = (f4*)(out + 131200000u);   // [4M] float4
    f4*    out_roi4    = (f4*)(out + 147200000u);   // [4M] float4

    unsigned int b = blockIdx.x;

    if (b < DEC_BLOCKS) {
        // ------- decode boxes: 1 box per thread, fully coalesced -------
        unsigned int tid  = b * 256u + threadIdx.x;     // [0, 16,000,000) exact
        unsigned int n    = tid / CM1;
        unsigned int cidx = tid - n * CM1;              // 0..79
        unsigned int c    = cidx + 1u;                  // class 1..80

        const float Wf = (float)img_w_p[0];
        const float Hf = (float)img_h_p[0];

        // proposal row: broadcast across the 80 threads of one n
        const f4 pr = proposals4[n];
        float w  = pr.z - pr.x;
        float h  = pr.w - pr.y;
        float cx = pr.x + 0.5f * w;
        float cy = pr.y + 0.5f * h;

        // deltas row n: 81 aligned float4s; plain cached load (L3 retention)
        const f4 d = box_reg4[(size_t)n * C_CLS + c];

        const float CLIP = 4.135166556742356f;  // log(1000/16)
        float dx = d.x * 0.1f;
        float dy = d.y * 0.1f;
        float dw = fminf(d.z * 0.2f, CLIP);
        float dh = fminf(d.w * 0.2f, CLIP);

        float pcx = dx * w + cx;
        float pcy = dy * h + cy;
        float pw  = expf(dw) * w;
        float ph  = expf(dh) * h;

        f4 bx;
        bx.x = fminf(fmaxf(pcx - 0.5f * pw, 0.0f), Wf);
        bx.y = fminf(fmaxf(pcy - 0.5f * ph, 0.0f), Hf);
        bx.z = fminf(fmaxf(pcx + 0.5f * pw, 0.0f), Wf);
        bx.w = fminf(fmaxf(pcy + 0.5f * ph, 0.0f), Hf);
        __builtin_nontemporal_store(bx, &out_boxes[tid]);
    } else if (b < CP_BASE) {
        // ------- softmax over 81 classes, drop class 0, LDS-staged f4 stores -------
        unsigned int wrel = threadIdx.x >> 6;                     // wave in block 0..3
        unsigned int row  = (b - SM_BASE) * 4u + wrel;            // row id, exact
        unsigned int lane = threadIdx.x & 63u;

        const float* rp = logits + (size_t)row * C_CLS;
        float v0 = rp[lane];
        float v1 = (lane < 17u) ? rp[64u + lane] : -INFINITY;

        float m = fmaxf(v0, v1);
        #pragma unroll
        for (int off = 32; off; off >>= 1) m = fmaxf(m, __shfl_xor(m, off, 64));

        float e0 = expf(v0 - m);
        float e1 = (lane < 17u) ? expf(v1 - m) : 0.0f;

        float s = e0 + e1;
        #pragma unroll
        for (int off = 32; off; off >>= 1) s += __shfl_xor(s, off, 64);

        float inv = 1.0f / s;
        float* srow = sbuf[wrel];
        if (lane >= 1u) srow[lane - 1u] = e0 * inv;
        if (lane < 17u) srow[63u + lane] = e1 * inv;
        __syncthreads();                       // block-uniform branch -> legal
        if (lane < 20u) {
            f4 v = ((const f4*)srow)[lane];    // 320B contiguous per row
            __builtin_nontemporal_store(v, &out_scores4[(size_t)row * 20u + lane]);
        }
    } else if (b < LR_BASE) {
        // ------- id_embedding copy: 2 float4 per thread, coalesced per instr -------
        unsigned int i = (b - CP_BASE) * 256u + threadIdx.x;      // [0, 6.4M)
        f4 a0 = id_emb4[i];
        f4 a1 = id_emb4[i + CP_HALF];
        __builtin_nontemporal_store(a0, &out_ids[i]);
        __builtin_nontemporal_store(a1, &out_ids[i + CP_HALF]);
    } else {
        // ------- labels + roi pure fill, float4 stores -------
        unsigned int j = (b - LR_BASE) * 256u + threadIdx.x;      // [0, 4M)
        unsigned int n  = j / 20u;
        unsigned int cb = (j - n * 20u) * 4u;
        f4 lv; lv.x = (float)(cb + 1u); lv.y = (float)(cb + 2u);
               lv.z = (float)(cb + 3u); lv.w = (float)(cb + 4u);
        float r = (float)(n % P_PER);
        f4 rv; rv.x = r; rv.y = r; rv.z = r; rv.w = r;
        __builtin_nontemporal_store(lv, &out_labels4[j]);
        __builtin_nontemporal_store(rv, &out_roi4[j]);
    }
}

extern "C" void kernel_launch(void* const* d_in, const int* in_sizes, int n_in,
                              void* d_out, int out_size, void* d_ws, size_t ws_size,
                              hipStream_t stream) {
    const float* class_logits = (const float*)d_in[0];  // [N,81]
    const float* box_reg      = (const float*)d_in[1];  // [N,324]
    const float* id_emb       = (const float*)d_in[2];  // [N,256]
    const float* proposals    = (const float*)d_in[3];  // [N,4]
    const int*   img_h        = (const int*)d_in[4];
    const int*   img_w        = (const int*)d_in[5];

    dim3 grid(DEC_BLOCKS + SM_BLOCKS + CP_BLOCKS + LR_BLOCKS), block(256);
    fused_kernel<<<grid, block, 0, stream>>>(
        class_logits, (const f4*)box_reg, (const f4*)id_emb, (const f4*)proposals,
        img_h, img_w, (float*)d_out);
}

// Round 8
// 217.614 us; speedup vs baseline: 1.0414x; 1.0414x over previous
//
#include <hip/hip_runtime.h>

// Problem constants (fixed by setup_inputs): B=8, P=25000, C=81, E=256, N=B*P=200000
#define N_TOT   200000
#define C_CLS   81
#define P_PER   25000
#define CM1     80            // C-1

// Output layout (float32 elements, concatenated in return order):
//   boxes   [N,80,4]  -> offset 0,           size 64,000,000
//   scores  [N,80]    -> offset 64,000,000,  size 16,000,000
//   id_embs [N,256]   -> offset 80,000,000,  size 51,200,000
//   labels  [N,80]    -> offset 131,200,000, size 16,000,000
//   roi     [N,80]    -> offset 147,200,000, size 16,000,000

typedef float f4 __attribute__((ext_vector_type(4)));

// Fused grid partition (256-thread blocks). Rules learned (A/B-verified):
//  R5: every wave-level NT store must cover a CONTIGUOUS span (lane i at
//      base + i*16B); scattered 16B fragments inflate WRITE_SIZE 1.6x.
//  R3: NT stores beat cached stores (~5%) for single-touch write streams.
//  R7: NT loads beat cached loads (~4%) — input doesn't fit L3; no-allocate
//      avoids thrash. NT-everything is the winning policy.
#define DEC_BLOCKS 62500u
#define SM_BLOCKS  50000u
#define CP_BLOCKS  25000u
#define LR_BLOCKS  15625u
#define SM_BASE    (DEC_BLOCKS)
#define CP_BASE    (DEC_BLOCKS + SM_BLOCKS)
#define LR_BASE    (DEC_BLOCKS + SM_BLOCKS + CP_BLOCKS)
#define CP_HALF    6400000u   // float4s per half of id_emb (12.8M / 2)

__global__ __launch_bounds__(256) void fused_kernel(
    const float* __restrict__ logits,      // [N, 81]
    const f4*    __restrict__ box_reg4,    // [N, 81] float4 rows
    const f4*    __restrict__ id_emb4,     // [N*64] float4
    const f4*    __restrict__ proposals4,  // [N]
    const int*   __restrict__ img_h_p,
    const int*   __restrict__ img_w_p,
    float* __restrict__ out)
{
    __shared__ float sbuf[4][80];                   // softmax row staging

    f4*    out_boxes   = (f4*)out;                  // [16M] float4
    f4*    out_scores4 = (f4*)(out + 64000000u);    // [4M]  float4 (80%4==0)
    f4*    out_ids     = (f4*)(out + 80000000u);
    f4*    out_labels4 = (f4*)(out + 131200000u);   // [4M] float4
    f4*    out_roi4    = (f4*)(out + 147200000u);   // [4M] float4

    unsigned int b = blockIdx.x;

    if (b < DEC_BLOCKS) {
        // ------- decode boxes: 1 box per thread, fully coalesced -------
        unsigned int tid  = b * 256u + threadIdx.x;     // [0, 16,000,000) exact
        unsigned int n    = tid / CM1;
        unsigned int cidx = tid - n * CM1;              // 0..79
        unsigned int c    = cidx + 1u;                  // class 1..80

        const float Wf = (float)img_w_p[0];
        const float Hf = (float)img_h_p[0];

        // proposal row: broadcast across the 80 threads of one n
        const f4 pr = proposals4[n];
        float w  = pr.z - pr.x;
        float h  = pr.w - pr.y;
        float cx = pr.x + 0.5f * w;
        float cy = pr.y + 0.5f * h;

        // deltas row n: 81 aligned float4s; streamed once -> nontemporal
        const f4 d = __builtin_nontemporal_load(&box_reg4[(size_t)n * C_CLS + c]);

        const float CLIP = 4.135166556742356f;  // log(1000/16)
        float dx = d.x * 0.1f;
        float dy = d.y * 0.1f;
        float dw = fminf(d.z * 0.2f, CLIP);
        float dh = fminf(d.w * 0.2f, CLIP);

        float pcx = dx * w + cx;
        float pcy = dy * h + cy;
        float pw  = expf(dw) * w;
        float ph  = expf(dh) * h;

        f4 bx;
        bx.x = fminf(fmaxf(pcx - 0.5f * pw, 0.0f), Wf);
        bx.y = fminf(fmaxf(pcy - 0.5f * ph, 0.0f), Hf);
        bx.z = fminf(fmaxf(pcx + 0.5f * pw, 0.0f), Wf);
        bx.w = fminf(fmaxf(pcy + 0.5f * ph, 0.0f), Hf);
        __builtin_nontemporal_store(bx, &out_boxes[tid]);
    } else if (b < CP_BASE) {
        // ------- softmax over 81 classes, drop class 0, LDS-staged f4 stores -------
        unsigned int wrel = threadIdx.x >> 6;                     // wave in block 0..3
        unsigned int row  = (b - SM_BASE) * 4u + wrel;            // row id, exact
        unsigned int lane = threadIdx.x & 63u;

        const float* rp = logits + (size_t)row * C_CLS;
        float v0 = __builtin_nontemporal_load(&rp[lane]);
        float v1 = (lane < 17u) ? __builtin_nontemporal_load(&rp[64u + lane]) : -INFINITY;

        float m = fmaxf(v0, v1);
        #pragma unroll
        for (int off = 32; off; off >>= 1) m = fmaxf(m, __shfl_xor(m, off, 64));

        float e0 = expf(v0 - m);
        float e1 = (lane < 17u) ? expf(v1 - m) : 0.0f;

        float s = e0 + e1;
        #pragma unroll
        for (int off = 32; off; off >>= 1) s += __shfl_xor(s, off, 64);

        float inv = 1.0f / s;
        float* srow = sbuf[wrel];
        if (lane >= 1u) srow[lane - 1u] = e0 * inv;
        if (lane < 17u) srow[63u + lane] = e1 * inv;
        __syncthreads();                       // block-uniform branch -> legal
        if (lane < 20u) {
            f4 v = ((const f4*)srow)[lane];    // 320B contiguous per row
            __builtin_nontemporal_store(v, &out_scores4[(size_t)row * 20u + lane]);
        }
    } else if (b < LR_BASE) {
        // ------- id_embedding copy: 2 float4 per thread, coalesced per instr -------
        unsigned int i = (b - CP_BASE) * 256u + threadIdx.x;      // [0, 6.4M)
        f4 a0 = __builtin_nontemporal_load(&id_emb4[i]);
        f4 a1 = __builtin_nontemporal_load(&id_emb4[i + CP_HALF]);
        __builtin_nontemporal_store(a0, &out_ids[i]);
        __builtin_nontemporal_store(a1, &out_ids[i + CP_HALF]);
    } else {
        // ------- labels + roi pure fill, float4 stores -------
        unsigned int j = (b - LR_BASE) * 256u + threadIdx.x;      // [0, 4M)
        unsigned int n  = j / 20u;
        unsigned int cb = (j - n * 20u) * 4u;
        f4 lv; lv.x = (float)(cb + 1u); lv.y = (float)(cb + 2u);
               lv.z = (float)(cb + 3u); lv.w = (float)(cb + 4u);
        float r = (float)(n % P_PER);
        f4 rv; rv.x = r; rv.y = r; rv.z = r; rv.w = r;
        __builtin_nontemporal_store(lv, &out_labels4[j]);
        __builtin_nontemporal_store(rv, &out_roi4[j]);
    }
}

extern "C" void kernel_launch(void* const* d_in, const int* in_sizes, int n_in,
                              void* d_out, int out_size, void* d_ws, size_t ws_size,
                              hipStream_t stream) {
    const float* class_logits = (const float*)d_in[0];  // [N,81]
    const float* box_reg      = (const float*)d_in[1];  // [N,324]
    const float* id_emb       = (const float*)d_in[2];  // [N,256]
    const float* proposals    = (const float*)d_in[3];  // [N,4]
    const int*   img_h        = (const int*)d_in[4];
    const int*   img_w        = (const int*)d_in[5];

    dim3 grid(DEC_BLOCKS + SM_BLOCKS + CP_BLOCKS + LR_BLOCKS), block(256);
    fused_kernel<<<grid, block, 0, stream>>>(
        class_logits, (const f4*)box_reg, (const f4*)id_emb, (const f4*)proposals,
        img_h, img_w, (float*)d_out);
}